// Round 12
// baseline (818.453 us; speedup 1.0000x reference)
//
#include <hip/hip_runtime.h>
#include <math.h>

typedef unsigned long long u64;
typedef unsigned int u32;

#define M_ANCH 360000
#define NCLS 80
#define KTOP 1000
#define CAP 8192
#define NBINS 65536
#define CONF_THRESH 0.05f
#define NMS_THRESH 0.6f
#define CTR_CLAMP 32.0f
#define SCALE_CLAMP 4.1351665567423560f  /* log(1000/16) */

/* bin of fkey(-1.0f): u=0xBF800000 -> ~u = 0x407FFFFF -> >>16 = 0x407F */
#define BIN_INVALID 0x407Fu

/* ---- workspace layout (bytes): zeroed region first, write-before-read after */
#define HIST_OFF   0u
#define B_OFF      (HIST_OFF + NBINS * 4u)        /* 262,144 */
#define N_OFF      (B_OFF + 4u)
#define PROBE_OFF  (B_OFF + 16u)                  /* 262,160, 16B aligned */
#define CAND_OFF   (B_OFF + 32u)                  /* 262,176, 16B aligned */
#define ZERO_END   (CAND_OFF + CAP * 8u)          /* cand zeroed (fallback safety) */
#define BINOFF_OFF ZERO_END                       /* 64K*4, fully written by k_boundary */
#define SC_OFF     (BINOFF_OFF + NBINS * 4u)      /* M floats */
#define CLS_OFF    (SC_OFF + M_ANCH * 4u)         /* M ints */
#define SSC_OFF    (CLS_OFF + M_ANCH * 4u)        /* 1000 floats */
#define SCLS_OFF   (SSC_OFF + KTOP * 4u)          /* 1000 ints */
#define SUP_OFF    ((SCLS_OFF + KTOP * 4u + 15u) & ~15u)  /* 16000 u64, 16B-aligned */

__device__ __forceinline__ u32 fkey(float f) {
    u32 u = __float_as_uint(f);
    return (u & 0x80000000u) ? ~u : (u | 0x80000000u);
}

/* K1: pure streaming score/argmax (no atomics). Block owns 64 anchors =
   1280 contiguous float4s = 20 KB. */
__global__ __launch_bounds__(256) void k_score(const float* __restrict__ cls_pred,
                                               float* __restrict__ sc_all,
                                               int* __restrict__ cls_all) {
    __shared__ float lm[64 * 21];
    __shared__ int   lc[64 * 21];
    int t = threadIdx.x;
    const float4* p = (const float4*)cls_pred + (size_t)blockIdx.x * 1280;
    float4 v0 = p[t];
    float4 v1 = p[t + 256];
    float4 v2 = p[t + 512];
    float4 v3 = p[t + 768];
    float4 v4 = p[t + 1024];
#pragma unroll
    for (int k = 0; k < 5; k++) {
        float4 v = (k == 0) ? v0 : (k == 1) ? v1 : (k == 2) ? v2 : (k == 3) ? v3 : v4;
        int f = t + 256 * k;      /* [0, 1280) */
        int a = f / 20;           /* local anchor [0, 64) */
        int s = f % 20;           /* slot [0, 20) */
        float mv = v.x; int mc = 0;
        if (v.y > mv) { mv = v.y; mc = 1; }
        if (v.z > mv) { mv = v.z; mc = 2; }
        if (v.w > mv) { mv = v.w; mc = 3; }
        lm[a * 21 + s] = mv;
        lc[a * 21 + s] = s * 4 + mc;
    }
    __syncthreads();
    if (t < 64) {
        float mv = -1e30f; int mc = 0;
#pragma unroll
        for (int s = 0; s < 20; s++) {
            float m = lm[t * 21 + s];
            int c = lc[t * 21 + s];
            if (m > mv) { mv = m; mc = c; }
        }
        int a = blockIdx.x * 64 + t;
        float sc = 1.0f / (1.0f + expf(-mv));
        sc_all[a] = sc;
        cls_all[a] = mc;
    }
}

/* PROBE (learning dispatch): m13-style pure read of all 115 MB of cls_pred.
   Grid-stride, no LDS, no sync, 5 independent loads in flight per thread.
   If this also runs at ~1.7 TB/s the read path is platform-capped; if it
   hits 5+ TB/s the k_score one-shot-block structure is the problem. */
#define PROBE_S 480000   /* 1875 blocks * 256 threads; 15 iters = 7.2M float4 */
__global__ __launch_bounds__(256) void k_probe(const float4* __restrict__ in,
                                               float4* __restrict__ scratch) {
    int tid = blockIdx.x * 256 + threadIdx.x;
    float4 acc = make_float4(0.f, 0.f, 0.f, 0.f);
#pragma unroll
    for (int k = 0; k < 15; k += 5) {
        float4 a = in[tid + (size_t)(k + 0) * PROBE_S];
        float4 b = in[tid + (size_t)(k + 1) * PROBE_S];
        float4 c = in[tid + (size_t)(k + 2) * PROBE_S];
        float4 d = in[tid + (size_t)(k + 3) * PROBE_S];
        float4 e = in[tid + (size_t)(k + 4) * PROBE_S];
        acc.x += a.x + b.x + c.x + d.x + e.x;
        acc.y += a.y + b.y + c.y + d.y + e.y;
        acc.z += a.z + b.z + c.z + d.z + e.z;
        acc.w += a.w + b.w + c.w + d.w + e.w;
    }
    if (acc.x + acc.y + acc.z + acc.w == 123456789.25f) scratch[0] = acc;
}

/* K1b: histogram of VALID anchors only (~4.7k atomics spread over ~1000
   bins). Rounds 10/11 measured same-address atomics at ~75 ns each (one L2
   round-trip, wave aggregation irrelevant) -> never histogram the 355k
   invalid anchors; k_boundary handles the (impossible here) <K-valid case. */
__global__ __launch_bounds__(256) void k_hist(const float* __restrict__ sc_all,
                                              u32* __restrict__ hist) {
    int i = blockIdx.x * 256 + threadIdx.x;
    if (i >= M_ANCH) return;
    float s = sc_all[i];
    if (s >= CONF_THRESH) atomicAdd(&hist[fkey(s) >> 16], 1u);
}

/* K2: boundary + per-bin suffix offsets. binoff[b] = count(bins > b) gives
   each bin a private contiguous slot range in cand, so k_compact needs no
   global counter (the 75 ns same-address serialization killer). Also finds
   B (count(bins >= B) >= KTOP) and writes exact candidate count outN. */
__global__ __launch_bounds__(1024) void k_boundary(const u32* __restrict__ hist,
                                                   u32* __restrict__ binoff,
                                                   u32* __restrict__ outB,
                                                   u32* __restrict__ outN) {
    __shared__ u32 csum[1024];
    int t = threadIdx.x;
    int base = t * 64;
    const ulonglong2* hp = (const ulonglong2*)(hist + base);
    u32 mysum = 0;
#pragma unroll
    for (int k = 0; k < 16; k++) {
        ulonglong2 w = hp[k];
        mysum += (u32)w.x + (u32)(w.x >> 32) + (u32)w.y + (u32)(w.y >> 32);
    }
    csum[t] = mysum;
    __syncthreads();
    u32 v = mysum;
    for (int off = 1; off < 1024; off <<= 1) {
        u32 add = (t + off < 1024) ? csum[t + off] : 0u;
        __syncthreads();
        v += add;
        csum[t] = v;
        __syncthreads();
    }
    u32 above = (t == 1023) ? 0u : csum[t + 1];
    u32 c = above;
    for (int k = 63; k >= 0; k--) {
        u32 h = hist[base + k];
        binoff[base + k] = c;                  /* count of elements in bins > this */
        if (c < KTOP && c + h >= KTOP) {       /* true for exactly one bin globally */
            outB[0] = (u32)(base + k);
            outN[0] = c + h;
        }
        c += h;
    }
    if (t == 0 && csum[0] < KTOP) {            /* fallback: fewer than K valid */
        outB[0] = BIN_INVALID;
        outN[0] = csum[0] + 2u * KTOP;         /* upper bound; cand is zeroed */
    }
}

/* K3: compact candidates into bin-private slot ranges. Positions are
   deterministic up to within-bin order, which k_rank's value-sort ignores. */
__global__ __launch_bounds__(256) void k_compact(const float* __restrict__ sc_all,
                                                 const u32* __restrict__ pB,
                                                 u32* __restrict__ binoff,
                                                 u64* __restrict__ cand) {
    int i = blockIdx.x * 256 + threadIdx.x;
    if (i >= M_ANCH) return;
    u32 B = *pB;
    float s = sc_all[i];
    bool valid = (s >= CONF_THRESH);
    float m = valid ? s : -1.0f;
    u32 u = fkey(m);
    u32 bin = u >> 16;
    if (bin >= B && (valid || i < 2 * KTOP)) {
        u32 pos = atomicAdd(&binoff[bin], 1u);
        if (pos < CAP) cand[pos] = ((u64)u << 32) | (u64)(0xFFFFFFFFu - (u32)i);
    }
}

/* K4: exact-rank selection. Thread t computes rank(t) = #{j : key_j >
   key_t} (keys unique via embedded index); if rank < 1000, decodes its box
   and scatters directly to position rank. */
__global__ __launch_bounds__(64) void k_rank(const u64* __restrict__ cand,
                                             const u32* __restrict__ pN,
                                             const float* __restrict__ sc_all,
                                             const int* __restrict__ cls_all,
                                             const float* __restrict__ reg_pred,
                                             const float* __restrict__ anchors,
                                             float* __restrict__ out,
                                             float* __restrict__ sel_sc,
                                             int* __restrict__ sel_cls) {
    u32 n = *pN;
    if (n > CAP) n = CAP;
    u32 t = blockIdx.x * 64 + threadIdx.x;
    if (t >= n) return;
    u64 mykey = cand[t];
    u32 rank = 0;
    const ulonglong2* cp = (const ulonglong2*)cand;
    u32 n4 = n >> 2;
    for (u32 g = 0; g < n4; g++) {
        ulonglong2 a = cp[2 * g], b = cp[2 * g + 1];
        rank += (a.x > mykey) + (a.y > mykey) + (b.x > mykey) + (b.y > mykey);
    }
    for (u32 j = n4 * 4; j < n; j++) rank += (cand[j] > mykey);
    if (rank < KTOP) {
        u32 idx = 0xFFFFFFFFu - (u32)(mykey & 0xFFFFFFFFull);
        if (idx >= M_ANCH) idx = 0;
        float s = sc_all[idx];
        int cl = cls_all[idx];
        float4 a = ((const float4*)anchors)[idx];
        float4 r = ((const float4*)reg_pred)[idx];
        float ox = fminf(fmaxf(r.x * a.z, -CTR_CLAMP), CTR_CLAMP);
        float oy = fminf(fmaxf(r.y * a.w, -CTR_CLAMP), CTR_CLAMP);
        float cx = a.x + ox, cy = a.y + oy;
        float ww = a.z * expf(fminf(r.z, SCALE_CLAMP));
        float hh = a.w * expf(fminf(r.w, SCALE_CLAMP));
        float4 box;
        box.x = cx - 0.5f * ww;
        box.y = cy - 0.5f * hh;
        box.z = cx + 0.5f * ww;
        box.w = cy + 0.5f * hh;
        ((float4*)out)[rank] = box;                /* boxes: out[0..3999] */
        out[5 * KTOP + rank] = (float)cl;          /* classes: out[5000..5999] */
        sel_sc[rank] = s;
        sel_cls[rank] = cl;
    }
}

/* K5: suppression matrix — one wave computes one 64-wide word via ballot */
__global__ __launch_bounds__(256) void k_supmat(const float* __restrict__ out,
                                                const int* __restrict__ sel_cls,
                                                u64* __restrict__ sup) {
    int wid = threadIdx.x >> 6;
    int lane = threadIdx.x & 63;
    int g = blockIdx.x * 4 + wid;          /* g in [0, 16000) */
    int i = g >> 4;
    int w = g & 15;
    int j = w * 64 + lane;
    int jc = (j < KTOP) ? j : (KTOP - 1);
    float4 bi = ((const float4*)out)[i];
    float4 bj = ((const float4*)out)[jc];
    int ci = sel_cls[i], cj = sel_cls[jc];
    float ai = (bi.z - bi.x) * (bi.w - bi.y);
    float aj = (bj.z - bj.x) * (bj.w - bj.y);
    float xx1 = fmaxf(bi.x, bj.x), yy1 = fmaxf(bi.y, bj.y);
    float xx2 = fminf(bi.z, bj.z), yy2 = fminf(bi.w, bj.w);
    float iw = fmaxf(1e-28f, xx2 - xx1), ih = fmaxf(1e-28f, yy2 - yy1);
    float inter = iw * ih;
    float iou = inter / (ai + aj - inter + 1e-14f);
    bool pred = (j < i) && (ci == cj) && (iou > NMS_THRESH);
    u64 bal = __ballot((int)pred);
    if (lane == 0) sup[g] = bal;
}

/* K6: greedy NMS, single wave, 16 blocks of 64 rows. Validity mask comes
   from one ballot over sel_sc per block (replaces the valid_words atomics). */
__global__ __launch_bounds__(64) void k_nms(const u64* __restrict__ sup,
                                            const float* __restrict__ sel_sc,
                                            float* __restrict__ out) {
    __shared__ u64 keepA[16];
    int lane = threadIdx.x;
    if (lane < 16) keepA[lane] = 0ull;
    __syncthreads();

    for (int b = 0; b < 16; b++) {
        int row = b * 64 + lane;
        int rowc = (row < KTOP) ? row : (KTOP - 1);
        const ulonglong2* rp = (const ulonglong2*)(sup + (size_t)rowc * 16);
        ulonglong2 q0 = rp[0], q1 = rp[1], q2 = rp[2], q3 = rp[3];
        ulonglong2 q4 = rp[4], q5 = rp[5], q6 = rp[6], q7 = rp[7];
        u64 d = sup[(size_t)rowc * 16 + b];   /* intra-block word */
        float sv = sel_sc[rowc];
        u64 vm = __ballot((int)((sv >= CONF_THRESH) && (row < KTOP)));

        u64 acc = (q0.x & keepA[0])  | (q0.y & keepA[1])
                | (q1.x & keepA[2])  | (q1.y & keepA[3])
                | (q2.x & keepA[4])  | (q2.y & keepA[5])
                | (q3.x & keepA[6])  | (q3.y & keepA[7])
                | (q4.x & keepA[8])  | (q4.y & keepA[9])
                | (q5.x & keepA[10]) | (q5.y & keepA[11])
                | (q6.x & keepA[12]) | (q6.y & keepA[13])
                | (q7.x & keepA[14]) | (q7.y & keepA[15]);
        u64 premask = __ballot(acc != 0ull);
        u64 eligible = vm & ~premask;

        u32 dlo = (u32)d, dhi = (u32)(d >> 32);
        u64 kb = 0ull;
#pragma unroll
        for (int j = 0; j < 64; j++) {
            u32 djl = __builtin_amdgcn_readlane(dlo, j);
            u32 djh = __builtin_amdgcn_readlane(dhi, j);
            u64 dj = ((u64)djh << 32) | (u64)djl;
            bool kj = (((eligible >> j) & 1ull) != 0ull) && ((dj & kb) == 0ull);
            kb |= ((u64)(kj ? 1u : 0u)) << j;
        }
        if (lane == 0) keepA[b] = kb;
        __syncthreads();
    }

    for (int t = lane; t < KTOP; t += 64) {
        int kb = (int)((keepA[t >> 6] >> (t & 63)) & 1ull);
        float s = sel_sc[t];
        out[4 * KTOP + t] = kb ? s : 0.0f;   /* scores*keep: out[4000..4999] */
        out[6 * KTOP + t] = (float)kb;       /* keep:        out[6000..6999] */
    }
}

extern "C" void kernel_launch(void* const* d_in, const int* in_sizes, int n_in,
                              void* d_out, int out_size, void* d_ws, size_t ws_size,
                              hipStream_t stream) {
    const float* cls_pred = (const float*)d_in[0];
    const float* reg_pred = (const float*)d_in[1];
    const float* anchors  = (const float*)d_in[2];
    float* out = (float*)d_out;
    char* ws = (char*)d_ws;

    u32* hist     = (u32*)(ws + HIST_OFF);
    u32* pB       = (u32*)(ws + B_OFF);
    u32* pN       = (u32*)(ws + N_OFF);
    float4* probe = (float4*)(ws + PROBE_OFF);
    u64* cand     = (u64*)(ws + CAND_OFF);
    u32* binoff   = (u32*)(ws + BINOFF_OFF);
    float* sc_all = (float*)(ws + SC_OFF);
    int* cls_all  = (int*)(ws + CLS_OFF);
    float* sel_sc = (float*)(ws + SSC_OFF);
    int* sel_cls  = (int*)(ws + SCLS_OFF);
    u64* sup      = (u64*)(ws + SUP_OFF);

    hipMemsetAsync(d_ws, 0, ZERO_END, stream);

    int nbs = M_ANCH / 64;            /* 5625 one-shot blocks, 64 anchors each */
    int nbc = (M_ANCH + 255) / 256;
    k_score<<<nbs, 256, 0, stream>>>(cls_pred, sc_all, cls_all);
    k_probe<<<PROBE_S / 256, 256, 0, stream>>>((const float4*)cls_pred, probe);
    k_hist<<<nbc, 256, 0, stream>>>(sc_all, hist);
    k_boundary<<<1, 1024, 0, stream>>>(hist, binoff, pB, pN);
    k_compact<<<nbc, 256, 0, stream>>>(sc_all, pB, binoff, cand);
    k_rank<<<CAP / 64, 64, 0, stream>>>(cand, pN, sc_all, cls_all, reg_pred,
                                        anchors, out, sel_sc, sel_cls);
    k_supmat<<<(KTOP * 16) / 4, 256, 0, stream>>>(out, sel_cls, sup);
    k_nms<<<1, 64, 0, stream>>>(sup, sel_sc, out);
}

// Round 13
// 406.462 us; speedup vs baseline: 2.0136x; 2.0136x over previous
//
#include <hip/hip_runtime.h>
#include <math.h>

typedef unsigned long long u64;
typedef unsigned int u32;

#define M_ANCH 360000
#define NCLS 80
#define KTOP 1000
#define CAP 8192
#define NBINS 65536
#define RREP 64
#define CONF_THRESH 0.05f
#define NMS_THRESH 0.6f
#define CTR_CLAMP 32.0f
#define SCALE_CLAMP 4.1351665567423560f  /* log(1000/16) */

#define BIN_INVALID 0x407Fu

/* ---- workspace layout (bytes): zeroed region first, write-before-read after */
#define HIST_OFF   0u
#define HIST_BYTES (RREP * NBINS * 4u)            /* 16 MB */
#define B_OFF      (HIST_OFF + HIST_BYTES)
#define N_OFF      (B_OFF + 4u)
#define PROBE_OFF  (B_OFF + 16u)                  /* 16B aligned */
#define CAND_OFF   (B_OFF + 32u)                  /* 16B aligned */
#define ZERO_END   (CAND_OFF + CAP * 8u)          /* zeroed region end */
#define MERGED_OFF ZERO_END                       /* 64K*4, written by k_hsum */
#define BINOFF_OFF (MERGED_OFF + NBINS * 4u)      /* 64K*4, written by k_boundary */
#define SC_OFF     (BINOFF_OFF + NBINS * 4u)      /* M floats */
#define CLS_OFF    (SC_OFF + M_ANCH * 4u)         /* M ints */
#define SSC_OFF    (CLS_OFF + M_ANCH * 4u)        /* 1000 floats */
#define SCLS_OFF   (SSC_OFF + KTOP * 4u)          /* 1000 ints */
#define SUP_OFF    ((SCLS_OFF + KTOP * 4u + 15u) & ~15u)  /* 16000 u64, 16B-aligned */

__device__ __forceinline__ u32 fkey(float f) {
    u32 u = __float_as_uint(f);
    return (u & 0x80000000u) ? ~u : (u | 0x80000000u);
}

/* K1: streaming score/argmax + 64-replica histogram. Data fact (round 12):
   max-of-80 N(-2,1) logits -> sigmoid in ~[0.5,0.9]; virtually ALL anchors
   pass CONF_THRESH, and scores concentrate in ~100 fkey bins, so hot bins
   hold thousands of entries. Same-address device atomics cost ~75 ns each
   (one L2 round-trip; wave-aggregation doesn't help across waves —
   rounds 10-12). 64 replicas divide the hot-bin chain to ~10 us, hidden
   under this kernel's own 67 us of memory work. */
__global__ __launch_bounds__(256) void k_score(const float* __restrict__ cls_pred,
                                               float* __restrict__ sc_all,
                                               int* __restrict__ cls_all,
                                               u32* __restrict__ hist) {
    __shared__ float lm[64 * 21];
    __shared__ int   lc[64 * 21];
    int t = threadIdx.x;
    const float4* p = (const float4*)cls_pred + (size_t)blockIdx.x * 1280;
    float4 v0 = p[t];
    float4 v1 = p[t + 256];
    float4 v2 = p[t + 512];
    float4 v3 = p[t + 768];
    float4 v4 = p[t + 1024];
#pragma unroll
    for (int k = 0; k < 5; k++) {
        float4 v = (k == 0) ? v0 : (k == 1) ? v1 : (k == 2) ? v2 : (k == 3) ? v3 : v4;
        int f = t + 256 * k;      /* [0, 1280) */
        int a = f / 20;           /* local anchor [0, 64) */
        int s = f % 20;           /* slot [0, 20) */
        float mv = v.x; int mc = 0;
        if (v.y > mv) { mv = v.y; mc = 1; }
        if (v.z > mv) { mv = v.z; mc = 2; }
        if (v.w > mv) { mv = v.w; mc = 3; }
        lm[a * 21 + s] = mv;
        lc[a * 21 + s] = s * 4 + mc;
    }
    __syncthreads();
    if (t < 64) {
        float mv = -1e30f; int mc = 0;
#pragma unroll
        for (int s = 0; s < 20; s++) {
            float m = lm[t * 21 + s];
            int c = lc[t * 21 + s];
            if (m > mv) { mv = m; mc = c; }
        }
        int a = blockIdx.x * 64 + t;
        float sc = 1.0f / (1.0f + expf(-mv));
        sc_all[a] = sc;
        cls_all[a] = mc;
        float msk = (sc >= CONF_THRESH) ? sc : -1.0f;
        u32 u = fkey(msk);
        atomicAdd(&hist[((u32)(blockIdx.x & (RREP - 1)) << 16) + (u >> 16)], 1u);
    }
}

/* PROBE (learning dispatch): m13-style pure read of all 115 MB of cls_pred.
   Decides whether k_score's ~1.7 TB/s is a platform read ceiling (probe
   ~65 us) or a structural artifact of the one-shot LDS blocks (~20 us). */
#define PROBE_S 480000   /* 1875 blocks * 256 threads; 15 iters = 7.2M float4 */
__global__ __launch_bounds__(256) void k_probe(const float4* __restrict__ in,
                                               float4* __restrict__ scratch) {
    int tid = blockIdx.x * 256 + threadIdx.x;
    float4 acc = make_float4(0.f, 0.f, 0.f, 0.f);
#pragma unroll
    for (int k = 0; k < 15; k += 5) {
        float4 a = in[tid + (size_t)(k + 0) * PROBE_S];
        float4 b = in[tid + (size_t)(k + 1) * PROBE_S];
        float4 c = in[tid + (size_t)(k + 2) * PROBE_S];
        float4 d = in[tid + (size_t)(k + 3) * PROBE_S];
        float4 e = in[tid + (size_t)(k + 4) * PROBE_S];
        acc.x += a.x + b.x + c.x + d.x + e.x;
        acc.y += a.y + b.y + c.y + d.y + e.y;
        acc.z += a.z + b.z + c.z + d.z + e.z;
        acc.w += a.w + b.w + c.w + d.w + e.w;
    }
    if (acc.x + acc.y + acc.z + acc.w == 123456789.25f) scratch[0] = acc;
}

/* K2a: merge the 64 histogram replicas (coalesced within each replica row) */
__global__ __launch_bounds__(1024) void k_hsum(const u32* __restrict__ hist,
                                               u32* __restrict__ merged) {
    int b = blockIdx.x * 1024 + threadIdx.x;
    u32 s = 0;
#pragma unroll 8
    for (int r = 0; r < RREP; r++) s += hist[(size_t)r * NBINS + b];
    merged[b] = s;
}

/* K2b: boundary + per-bin suffix offsets from merged histogram.
   binoff[b] = count(bins > b): bin-private slot ranges for k_compact
   (no global counter -> no same-address atomic serialization). */
__global__ __launch_bounds__(1024) void k_boundary(const u32* __restrict__ merged,
                                                   u32* __restrict__ binoff,
                                                   u32* __restrict__ outB,
                                                   u32* __restrict__ outN) {
    __shared__ u32 csum[1024];
    int t = threadIdx.x;
    int base = t * 64;
    const ulonglong2* hp = (const ulonglong2*)(merged + base);
    u32 mysum = 0;
#pragma unroll
    for (int k = 0; k < 16; k++) {
        ulonglong2 w = hp[k];
        mysum += (u32)w.x + (u32)(w.x >> 32) + (u32)w.y + (u32)(w.y >> 32);
    }
    csum[t] = mysum;
    __syncthreads();
    u32 v = mysum;
    for (int off = 1; off < 1024; off <<= 1) {
        u32 add = (t + off < 1024) ? csum[t + off] : 0u;
        __syncthreads();
        v += add;
        csum[t] = v;
        __syncthreads();
    }
    u32 above = (t == 1023) ? 0u : csum[t + 1];
    u32 c = above;
    for (int k = 63; k >= 0; k--) {
        u32 h = merged[base + k];
        binoff[base + k] = c;                  /* count of elements in bins > this */
        if (c < KTOP && c + h >= KTOP) {       /* true for exactly one bin globally */
            outB[0] = (u32)(base + k);
            outN[0] = c + h;
        }
        c += h;
    }
    if (t == 0 && csum[0] < KTOP) {            /* fallback: fewer than K candidates */
        outB[0] = 0u;
        outN[0] = csum[0];
    }
}

/* K3: compact candidates into bin-private slot ranges. */
__global__ __launch_bounds__(256) void k_compact(const float* __restrict__ sc_all,
                                                 const u32* __restrict__ pB,
                                                 u32* __restrict__ binoff,
                                                 u64* __restrict__ cand) {
    int i = blockIdx.x * 256 + threadIdx.x;
    if (i >= M_ANCH) return;
    u32 B = *pB;
    float s = sc_all[i];
    float m = (s >= CONF_THRESH) ? s : -1.0f;
    u32 u = fkey(m);
    u32 bin = u >> 16;
    if (bin >= B) {
        u32 pos = atomicAdd(&binoff[bin], 1u);
        if (pos < CAP) cand[pos] = ((u64)u << 32) | (u64)(0xFFFFFFFFu - (u32)i);
    }
}

/* K4: exact-rank selection: rank(t) = #{j: key_j > key_t}; scatter to rank. */
__global__ __launch_bounds__(64) void k_rank(const u64* __restrict__ cand,
                                             const u32* __restrict__ pN,
                                             const float* __restrict__ sc_all,
                                             const int* __restrict__ cls_all,
                                             const float* __restrict__ reg_pred,
                                             const float* __restrict__ anchors,
                                             float* __restrict__ out,
                                             float* __restrict__ sel_sc,
                                             int* __restrict__ sel_cls) {
    u32 n = *pN;
    if (n > CAP) n = CAP;
    u32 t = blockIdx.x * 64 + threadIdx.x;
    if (t >= n) return;
    u64 mykey = cand[t];
    u32 rank = 0;
    const ulonglong2* cp = (const ulonglong2*)cand;
    u32 n4 = n >> 2;
    for (u32 g = 0; g < n4; g++) {
        ulonglong2 a = cp[2 * g], b = cp[2 * g + 1];
        rank += (a.x > mykey) + (a.y > mykey) + (b.x > mykey) + (b.y > mykey);
    }
    for (u32 j = n4 * 4; j < n; j++) rank += (cand[j] > mykey);
    if (rank < KTOP) {
        u32 idx = 0xFFFFFFFFu - (u32)(mykey & 0xFFFFFFFFull);
        if (idx >= M_ANCH) idx = 0;
        float s = sc_all[idx];
        int cl = cls_all[idx];
        float4 a = ((const float4*)anchors)[idx];
        float4 r = ((const float4*)reg_pred)[idx];
        float ox = fminf(fmaxf(r.x * a.z, -CTR_CLAMP), CTR_CLAMP);
        float oy = fminf(fmaxf(r.y * a.w, -CTR_CLAMP), CTR_CLAMP);
        float cx = a.x + ox, cy = a.y + oy;
        float ww = a.z * expf(fminf(r.z, SCALE_CLAMP));
        float hh = a.w * expf(fminf(r.w, SCALE_CLAMP));
        float4 box;
        box.x = cx - 0.5f * ww;
        box.y = cy - 0.5f * hh;
        box.z = cx + 0.5f * ww;
        box.w = cy + 0.5f * hh;
        ((float4*)out)[rank] = box;                /* boxes: out[0..3999] */
        out[5 * KTOP + rank] = (float)cl;          /* classes: out[5000..5999] */
        sel_sc[rank] = s;
        sel_cls[rank] = cl;
    }
}

/* K5: suppression matrix — one wave computes one 64-wide word via ballot */
__global__ __launch_bounds__(256) void k_supmat(const float* __restrict__ out,
                                                const int* __restrict__ sel_cls,
                                                u64* __restrict__ sup) {
    int wid = threadIdx.x >> 6;
    int lane = threadIdx.x & 63;
    int g = blockIdx.x * 4 + wid;          /* g in [0, 16000) */
    int i = g >> 4;
    int w = g & 15;
    int j = w * 64 + lane;
    int jc = (j < KTOP) ? j : (KTOP - 1);
    float4 bi = ((const float4*)out)[i];
    float4 bj = ((const float4*)out)[jc];
    int ci = sel_cls[i], cj = sel_cls[jc];
    float ai = (bi.z - bi.x) * (bi.w - bi.y);
    float aj = (bj.z - bj.x) * (bj.w - bj.y);
    float xx1 = fmaxf(bi.x, bj.x), yy1 = fmaxf(bi.y, bj.y);
    float xx2 = fminf(bi.z, bj.z), yy2 = fminf(bi.w, bj.w);
    float iw = fmaxf(1e-28f, xx2 - xx1), ih = fmaxf(1e-28f, yy2 - yy1);
    float inter = iw * ih;
    float iou = inter / (ai + aj - inter + 1e-14f);
    bool pred = (j < i) && (ci == cj) && (iou > NMS_THRESH);
    u64 bal = __ballot((int)pred);
    if (lane == 0) sup[g] = bal;
}

/* K6: greedy NMS, single wave, 16 blocks of 64 rows. */
__global__ __launch_bounds__(64) void k_nms(const u64* __restrict__ sup,
                                            const float* __restrict__ sel_sc,
                                            float* __restrict__ out) {
    __shared__ u64 keepA[16];
    int lane = threadIdx.x;
    if (lane < 16) keepA[lane] = 0ull;
    __syncthreads();

    for (int b = 0; b < 16; b++) {
        int row = b * 64 + lane;
        int rowc = (row < KTOP) ? row : (KTOP - 1);
        const ulonglong2* rp = (const ulonglong2*)(sup + (size_t)rowc * 16);
        ulonglong2 q0 = rp[0], q1 = rp[1], q2 = rp[2], q3 = rp[3];
        ulonglong2 q4 = rp[4], q5 = rp[5], q6 = rp[6], q7 = rp[7];
        u64 d = sup[(size_t)rowc * 16 + b];   /* intra-block word */
        float sv = sel_sc[rowc];
        u64 vm = __ballot((int)((sv >= CONF_THRESH) && (row < KTOP)));

        u64 acc = (q0.x & keepA[0])  | (q0.y & keepA[1])
                | (q1.x & keepA[2])  | (q1.y & keepA[3])
                | (q2.x & keepA[4])  | (q2.y & keepA[5])
                | (q3.x & keepA[6])  | (q3.y & keepA[7])
                | (q4.x & keepA[8])  | (q4.y & keepA[9])
                | (q5.x & keepA[10]) | (q5.y & keepA[11])
                | (q6.x & keepA[12]) | (q6.y & keepA[13])
                | (q7.x & keepA[14]) | (q7.y & keepA[15]);
        u64 premask = __ballot(acc != 0ull);
        u64 eligible = vm & ~premask;

        u32 dlo = (u32)d, dhi = (u32)(d >> 32);
        u64 kb = 0ull;
#pragma unroll
        for (int j = 0; j < 64; j++) {
            u32 djl = __builtin_amdgcn_readlane(dlo, j);
            u32 djh = __builtin_amdgcn_readlane(dhi, j);
            u64 dj = ((u64)djh << 32) | (u64)djl;
            bool kj = (((eligible >> j) & 1ull) != 0ull) && ((dj & kb) == 0ull);
            kb |= ((u64)(kj ? 1u : 0u)) << j;
        }
        if (lane == 0) keepA[b] = kb;
        __syncthreads();
    }

    for (int t = lane; t < KTOP; t += 64) {
        int kb = (int)((keepA[t >> 6] >> (t & 63)) & 1ull);
        float s = sel_sc[t];
        out[4 * KTOP + t] = kb ? s : 0.0f;   /* scores*keep: out[4000..4999] */
        out[6 * KTOP + t] = (float)kb;       /* keep:        out[6000..6999] */
    }
}

extern "C" void kernel_launch(void* const* d_in, const int* in_sizes, int n_in,
                              void* d_out, int out_size, void* d_ws, size_t ws_size,
                              hipStream_t stream) {
    const float* cls_pred = (const float*)d_in[0];
    const float* reg_pred = (const float*)d_in[1];
    const float* anchors  = (const float*)d_in[2];
    float* out = (float*)d_out;
    char* ws = (char*)d_ws;

    u32* hist     = (u32*)(ws + HIST_OFF);
    u32* pB       = (u32*)(ws + B_OFF);
    u32* pN       = (u32*)(ws + N_OFF);
    float4* probe = (float4*)(ws + PROBE_OFF);
    u64* cand     = (u64*)(ws + CAND_OFF);
    u32* merged   = (u32*)(ws + MERGED_OFF);
    u32* binoff   = (u32*)(ws + BINOFF_OFF);
    float* sc_all = (float*)(ws + SC_OFF);
    int* cls_all  = (int*)(ws + CLS_OFF);
    float* sel_sc = (float*)(ws + SSC_OFF);
    int* sel_cls  = (int*)(ws + SCLS_OFF);
    u64* sup      = (u64*)(ws + SUP_OFF);

    hipMemsetAsync(d_ws, 0, ZERO_END, stream);

    int nbs = M_ANCH / 64;            /* 5625 one-shot blocks, 64 anchors each */
    int nbc = (M_ANCH + 255) / 256;
    k_score<<<nbs, 256, 0, stream>>>(cls_pred, sc_all, cls_all, hist);
    k_probe<<<PROBE_S / 256, 256, 0, stream>>>((const float4*)cls_pred, probe);
    k_hsum<<<NBINS / 1024, 1024, 0, stream>>>(hist, merged);
    k_boundary<<<1, 1024, 0, stream>>>(merged, binoff, pB, pN);
    k_compact<<<nbc, 256, 0, stream>>>(sc_all, pB, binoff, cand);
    k_rank<<<CAP / 64, 64, 0, stream>>>(cand, pN, sc_all, cls_all, reg_pred,
                                        anchors, out, sel_sc, sel_cls);
    k_supmat<<<(KTOP * 16) / 4, 256, 0, stream>>>(out, sel_cls, sup);
    k_nms<<<1, 64, 0, stream>>>(sup, sel_sc, out);
}